// Round 5
// baseline (1106.996 us; speedup 1.0000x reference)
//
#include <hip/hip_runtime.h>
#include <hip/hip_bf16.h>

#define NODES   50000
#define EDGES   1600000
#define DIM     128
#define ROWS    98         // rows per agg tile
#define NT      511        // row tiles: ceil(50000/98)
#define BSTR    3712       // per-tile edge capacity (mean 3136, +10 sigma)
#define NCB     196        // col buckets of 256 within a tile
#define TILE    8192       // edges per binA block
#define EPT     32
#define NTILES  196

typedef unsigned int   u32;
typedef unsigned short u16;
typedef __attribute__((ext_vector_type(4))) float f32x4;
typedef __attribute__((ext_vector_type(8))) short s16x8;

__device__ inline u16 f2bf(float f) {
  __hip_bfloat16 h = __float2bfloat16(f);
  return *reinterpret_cast<u16*>(&h);
}

// exact floor(r/98) for r < 50000
__device__ inline int rowbkt(u32 r) {
  return (int)(((unsigned long long)r * 43826197ull) >> 32);
}

// ---------------- init bucket cursors ----------------
__global__ void k_init(int* __restrict__ gcursor) {
  int i = blockIdx.x * 256 + threadIdx.x;
  if (i < NT) gcursor[i] = i * BSTR;
}

// ---------------- W -> WT bf16, pre-swizzled: wts[c][k^((c&15)<<3)] ----------------
__global__ __launch_bounds__(256) void k_prep(const float* __restrict__ W,
                                              u16* __restrict__ wts) {
  __shared__ float T[32 * 132];
  int t = threadIdx.x;
  int c0 = blockIdx.x * 32;
#pragma unroll
  for (int i = 0; i < 16; ++i) {
    int idx = i * 256 + t;
    int k = idx >> 5;
    int cc = idx & 31;
    T[cc * 132 + k] = W[k * 128 + c0 + cc];
  }
  __syncthreads();
#pragma unroll
  for (int i = 0; i < 2; ++i) {
    int idx = i * 256 + t;
    int cc = idx >> 4;
    int kc = idx & 15;
    int c = c0 + cc;
    int kbase = kc * 8;
    u32 p[4];
#pragma unroll
    for (int u = 0; u < 4; ++u) {
      float a = T[cc * 132 + kbase + 2 * u];
      float b = T[cc * 132 + kbase + 2 * u + 1];
      p[u] = (u32)f2bf(a) | ((u32)f2bf(b) << 16);
    }
    int off = c * 256 + ((kbase * 2) ^ ((c & 15) << 4));
    *(uint4*)((char*)wts + off) = make_uint4(p[0], p[1], p[2], p[3]);
  }
}

// ---------------- bin pass A: edges -> row-tile regions (r,c packed u32) ----------------
__global__ __launch_bounds__(256) void k_binA(const int* __restrict__ erow,
                                              const int* __restrict__ ecol,
                                              int* __restrict__ gcursor,
                                              u32* __restrict__ binned) {
  __shared__ int hist[NT];
  __shared__ int lcur[NT];
  int t = threadIdx.x;
  for (int b = t; b < NT; b += 256) hist[b] = 0;
  __syncthreads();
  int base = blockIdx.x * TILE;
  u32 v[EPT];
#pragma unroll
  for (int k = 0; k < EPT; ++k) {
    int e = base + k * 256 + t;
    if (e < EDGES) {
      u32 r = (u32)erow[e], c = (u32)ecol[e];
      v[k] = (r << 16) | c;
      atomicAdd(&hist[rowbkt(r)], 1);
    } else v[k] = 0xffffffffu;
  }
  __syncthreads();
  for (int b = t; b < NT; b += 256) {
    int h = hist[b];
    lcur[b] = h ? atomicAdd(&gcursor[b], h) : 0;
  }
  __syncthreads();
#pragma unroll
  for (int k = 0; k < EPT; ++k) {
    if (v[k] != 0xffffffffu) {
      int bkt = rowbkt(v[k] >> 16);
      int pos = atomicAdd(&lcur[bkt], 1);
      if (pos < (bkt + 1) * BSTR) binned[pos] = v[k];   // overflow clamp (never hit)
    }
  }
}

// ---------------- bin pass C: col-sort within tile + per-node degrees ----------------
__global__ __launch_bounds__(256) void k_binC(const u32* __restrict__ binned,
                                              const int* __restrict__ gcur,
                                              u32* __restrict__ colsorted,
                                              int* __restrict__ deg) {
  __shared__ int hist[NCB];
  __shared__ int lcur[NCB];
  __shared__ int dcnt[ROWS];
  __shared__ int sc[256];
  int b = blockIdx.x;
  int t = threadIdx.x;
  int n0 = b * ROWS;
  int s = b * BSTR;
  int cnt = gcur[b] - s;
  if (cnt > BSTR) cnt = BSTR;
  int e = s + cnt;
  for (int i = t; i < NCB; i += 256) hist[i] = 0;
  if (t < ROWS) dcnt[t] = 0;
  __syncthreads();
  for (int j = s + t; j < e; j += 256) {
    u32 v = binned[j];
    atomicAdd(&hist[(v & 0xffffu) >> 8], 1);
    atomicAdd(&dcnt[(int)(v >> 16) - n0], 1);
  }
  __syncthreads();
  int hv = (t < NCB) ? hist[t] : 0;
  sc[t] = hv;
  __syncthreads();
  for (int off = 1; off < 256; off <<= 1) {
    int tmp = (t >= off) ? sc[t - off] : 0;
    __syncthreads();
    sc[t] += tmp;
    __syncthreads();
  }
  if (t < NCB) lcur[t] = s + sc[t] - hv;   // exclusive prefix + tile base
  if (t < ROWS) {
    int n = n0 + t;
    if (n < NODES) deg[n] = dcnt[t];
  }
  __syncthreads();
  for (int j = s + t; j < e; j += 256) {
    u32 v = binned[j];
    int pos = atomicAdd(&lcur[(v & 0xffffu) >> 8], 1);
    colsorted[pos] = v;
  }
}

// ---------------- y2 = diag(deg^-1/2) * (x @ W) via MFMA, stored bf16 ----------------
__global__ __launch_bounds__(256) void k_gemm(const float* __restrict__ x,
                                              const u16* __restrict__ wts,
                                              const int* __restrict__ deg,
                                              u16* __restrict__ y2) {
  __shared__ u16 xs[64 * 128];
  __shared__ u16 ws[128 * 128];
  const int t = threadIdx.x;
  const int bb = blockIdx.x * 64;

  {
    const uint4* src = (const uint4*)wts;
    uint4* dst = (uint4*)ws;
#pragma unroll
    for (int i = 0; i < 8; ++i) dst[i * 256 + t] = src[i * 256 + t];
  }
  {
#pragma unroll
    for (int i = 0; i < 8; ++i) {
      int goff = i * 4096 + t * 16;
      int row = goff >> 9;
      int gr = bb + row;
      float4 v = make_float4(0.f, 0.f, 0.f, 0.f);
      if (gr < NODES) v = *(const float4*)((const char*)x + (size_t)gr * 512 + (goff & 511));
      u32 lo = (u32)f2bf(v.x) | ((u32)f2bf(v.y) << 16);
      u32 hi = (u32)f2bf(v.z) | ((u32)f2bf(v.w) << 16);
      int colb = (goff & 511) >> 1;
      int off = row * 256 + (colb ^ ((row & 15) << 4));
      *(uint2*)((char*)xs + off) = make_uint2(lo, hi);
    }
  }
  __syncthreads();

  const int w = t >> 6, l = t & 63, m = l & 15, g = l >> 4;
  f32x4 acc[8];
#pragma unroll
  for (int j = 0; j < 8; ++j) acc[j] = (f32x4)0.0f;

  const char* xb = (const char*)xs;
  const char* wb = (const char*)ws;
  const int arow = w * 16 + m;
#pragma unroll
  for (int s = 0; s < 4; ++s) {
    int kx = (g * 16 + s * 64) ^ (m << 4);
    s16x8 a = *(const s16x8*)(xb + arow * 256 + kx);
#pragma unroll
    for (int j = 0; j < 8; ++j) {
      s16x8 b = *(const s16x8*)(wb + (j * 16 + m) * 256 + kx);
      acc[j] = __builtin_amdgcn_mfma_f32_16x16x32_bf16(a, b, acc[j], 0, 0, 0);
    }
  }

  int rbase = bb + w * 16 + g * 4;
  int4 dd = *(const int4*)&deg[rbase];     // deg padded past 50000
  float dv0 = rsqrtf((float)dd.x);
  float dv1 = rsqrtf((float)dd.y);
  float dv2 = rsqrtf((float)dd.z);
  float dv3 = rsqrtf((float)dd.w);
#pragma unroll
  for (int j = 0; j < 8; ++j) {
#pragma unroll
    for (int r = 0; r < 4; ++r) {
      int gr = rbase + r;
      if (gr < NODES) {
        float dv = (r == 0) ? dv0 : (r == 1) ? dv1 : (r == 2) ? dv2 : dv3;
        y2[(size_t)gr * 128 + j * 16 + m] = f2bf(acc[j][r] * dv);
      }
    }
  }
}

__device__ inline void acc8(float* a, uint4 g) {
  atomicAdd(&a[0], __uint_as_float(g.x << 16));
  atomicAdd(&a[1], __uint_as_float(g.x & 0xffff0000u));
  atomicAdd(&a[2], __uint_as_float(g.y << 16));
  atomicAdd(&a[3], __uint_as_float(g.y & 0xffff0000u));
  atomicAdd(&a[4], __uint_as_float(g.z << 16));
  atomicAdd(&a[5], __uint_as_float(g.z & 0xffff0000u));
  atomicAdd(&a[6], __uint_as_float(g.w << 16));
  atomicAdd(&a[7], __uint_as_float(g.w & 0xffff0000u));
}

// ---------------- aggregation: per-row-tile LDS fp32 accumulators, col-ordered gathers ----------------
__global__ __launch_bounds__(1024) void k_agg2(const u16* __restrict__ y2,
                                               const u32* __restrict__ colsorted,
                                               const int* __restrict__ gcur,
                                               const int* __restrict__ deg,
                                               const float* __restrict__ bias,
                                               float* __restrict__ out) {
  extern __shared__ float acc[];           // ROWS * 129 floats
  const int b = blockIdx.x;
  const int n0 = b * ROWS;
  const int t = threadIdx.x;
  const int s = b * BSTR;
  int cnt = gcur[b] - s;
  if (cnt > BSTR) cnt = BSTR;
  const int e = s + cnt;

  for (int i = t; i < ROWS * 129; i += 1024) acc[i] = 0.0f;
  __syncthreads();

  const int w = t >> 6, l = t & 63, q = l >> 4, m = l & 15;
  const uint4* yb = (const uint4*)y2;
  int iters = (cnt + 63) >> 6;

  int idx = s + w * 4 + q;
  bool val = idx < e;
  u32 v = val ? colsorted[idx] : 0u;
  uint4 g = yb[(int)(v & 0xffffu) * 16 + m];
  for (int i = 1; i < iters; ++i) {
    int idx2 = s + i * 64 + w * 4 + q;
    bool val2 = idx2 < e;
    u32 v2 = val2 ? colsorted[idx2] : 0u;
    uint4 g2 = yb[(int)(v2 & 0xffffu) * 16 + m];
    if (val) acc8(&acc[((int)(v >> 16) - n0) * 129 + m * 8], g);
    v = v2; g = g2; val = val2;
  }
  if (val) acc8(&acc[((int)(v >> 16) - n0) * 129 + m * 8], g);
  __syncthreads();

  // epilogue: thread -> (row = t>>3, 16-col segment = (t&7)*16)
  int r = t >> 3;
  if (r < ROWS) {
    int gr = n0 + r;
    if (gr < NODES) {
      int dg = deg[gr];
      float di = (dg > 0) ? rsqrtf((float)dg) : 0.0f;
      const float* arow = &acc[r * 129 + (t & 7) * 16];
      int cbase = (t & 7) * 16;
#pragma unroll
      for (int u = 0; u < 4; ++u) {
        float4 bb = *(const float4*)&bias[cbase + u * 4];
        float4 o;
        o.x = bb.x + di * arow[u * 4 + 0];
        o.y = bb.y + di * arow[u * 4 + 1];
        o.z = bb.z + di * arow[u * 4 + 2];
        o.w = bb.w + di * arow[u * 4 + 3];
        *(float4*)&out[(size_t)gr * 128 + cbase + u * 4] = o;
      }
    }
  }
}

extern "C" void kernel_launch(void* const* d_in, const int* in_sizes, int n_in,
                              void* d_out, int out_size, void* d_ws, size_t ws_size,
                              hipStream_t stream) {
  const float* x    = (const float*)d_in[0];
  const float* W    = (const float*)d_in[1];
  const float* bias = (const float*)d_in[2];
  const int*   erow = (const int*)d_in[3];
  const int*   ecol = (const int*)d_in[4];
  float* out = (float*)d_out;

  char* ws = (char*)d_ws;
  int*   gcursor   = (int*)(ws + 0);           // 2 KB
  int*   deg       = (int*)(ws + 4096);        // 200 KB (padded to 50048)
  u16*   wts       = (u16*)(ws + 204800);      // 32 KB
  u32*   binned    = (u32*)(ws + 241664);      // 7.59 MB
  u32*   colsorted = (u32*)(ws + 7829504);     // 7.59 MB
  u16*   y2        = (u16*)(ws + 15417344);    // 12.8 MB  (total ~28.2 MB)

  k_init<<<2, 256, 0, stream>>>(gcursor);
  k_prep<<<4, 256, 0, stream>>>(W, wts);
  k_binA<<<NTILES, 256, 0, stream>>>(erow, ecol, gcursor, binned);
  k_binC<<<NT, 256, 0, stream>>>(binned, gcursor, colsorted, deg);
  k_gemm<<<(NODES + 63) / 64, 256, 0, stream>>>(x, wts, deg, y2);
  k_agg2<<<NT, 1024, ROWS * 129 * 4, stream>>>(y2, colsorted, gcursor, deg, bias, out);
}

// Round 8
// 117.310 us; speedup vs baseline: 9.4365x; 9.4365x over previous
//
#include <hip/hip_runtime.h>
#include <hip/hip_bf16.h>

#define NODES   50000
#define EDGES   1600000
#define DIM     128
#define NB      391        // buckets of 128 nodes
#define BSTRIDE 4608       // fixed bucket capacity (mean 4092, +8 sigma)
#define TILE    8192
#define EPT     32
#define NTILES  196

typedef unsigned int   u32;
typedef unsigned short u16;
typedef __attribute__((ext_vector_type(4))) float f32x4;
typedef __attribute__((ext_vector_type(8))) short s16x8;

__device__ inline u16 f2bf(float f) {
  __hip_bfloat16 h = __float2bfloat16(f);
  return *reinterpret_cast<u16*>(&h);
}

// ---------------- W -> WT bf16 pre-swizzled + gcursor init (fused) ----------------
__global__ __launch_bounds__(256) void k_prep(const float* __restrict__ W,
                                              u16* __restrict__ wts,
                                              int* __restrict__ gcursor) {
  __shared__ float T[32 * 132];
  int t = threadIdx.x;
  int gi = blockIdx.x * 256 + t;
  if (gi < NB) gcursor[gi] = gi * BSTRIDE;
  int c0 = blockIdx.x * 32;
#pragma unroll
  for (int i = 0; i < 16; ++i) {
    int idx = i * 256 + t;            // 4096 = 128k x 32c
    int k = idx >> 5;
    int cc = idx & 31;
    T[cc * 132 + k] = W[k * 128 + c0 + cc];
  }
  __syncthreads();
#pragma unroll
  for (int i = 0; i < 2; ++i) {
    int idx = i * 256 + t;            // 512 = 32c x 16 chunks
    int cc = idx >> 4;
    int kc = idx & 15;
    int c = c0 + cc;
    int kbase = kc * 8;
    u32 p[4];
#pragma unroll
    for (int u = 0; u < 4; ++u) {
      float a = T[cc * 132 + kbase + 2 * u];
      float b = T[cc * 132 + kbase + 2 * u + 1];
      p[u] = (u32)f2bf(a) | ((u32)f2bf(b) << 16);
    }
    int off = c * 256 + ((kbase * 2) ^ ((c & 15) << 4));
    *(uint4*)((char*)wts + off) = make_uint4(p[0], p[1], p[2], p[3]);
  }
}

// ---------------- bin pass A: edges -> bucket regions (r,c packed u32), int4 loads ----------------
__global__ __launch_bounds__(256) void k_binA(const int* __restrict__ erow,
                                              const int* __restrict__ ecol,
                                              int* __restrict__ gcursor,
                                              u32* __restrict__ binned) {
  __shared__ int hist[NB];
  __shared__ int lcur[NB];
  int t = threadIdx.x;
  for (int b = t; b < NB; b += 256) hist[b] = 0;
  __syncthreads();
  int base = blockIdx.x * TILE;
  u32 v[EPT];
#pragma unroll
  for (int k = 0; k < 8; ++k) {
    int e4 = base + k * 1024 + t * 4;   // EDGES % 4 == 0, e4 % 4 == 0 -> full int4 in-bounds
    if (e4 < EDGES) {
      int4 rr = *(const int4*)&erow[e4];
      int4 cc = *(const int4*)&ecol[e4];
      v[k * 4 + 0] = ((u32)rr.x << 16) | (u32)cc.x;
      v[k * 4 + 1] = ((u32)rr.y << 16) | (u32)cc.y;
      v[k * 4 + 2] = ((u32)rr.z << 16) | (u32)cc.z;
      v[k * 4 + 3] = ((u32)rr.w << 16) | (u32)cc.w;
      atomicAdd(&hist[(u32)rr.x >> 7], 1);
      atomicAdd(&hist[(u32)rr.y >> 7], 1);
      atomicAdd(&hist[(u32)rr.z >> 7], 1);
      atomicAdd(&hist[(u32)rr.w >> 7], 1);
    } else {
      v[k * 4 + 0] = 0xffffffffu;
      v[k * 4 + 1] = 0xffffffffu;
      v[k * 4 + 2] = 0xffffffffu;
      v[k * 4 + 3] = 0xffffffffu;
    }
  }
  __syncthreads();
  for (int b = t; b < NB; b += 256) {
    int h = hist[b];
    lcur[b] = h ? atomicAdd(&gcursor[b], h) : 0;
  }
  __syncthreads();
#pragma unroll
  for (int k = 0; k < EPT; ++k) {
    if (v[k] != 0xffffffffu) {
      int b = (int)(v[k] >> 23);
      int pos = atomicAdd(&lcur[b], 1);
      if (pos < (b + 1) * BSTRIDE) binned[pos] = v[k];   // overflow clamp (never hit)
    }
  }
}

// ---------------- bin pass B (R4 verbatim): per-node counts + rpS/rpE + dis + cols (u16) ----------------
__global__ __launch_bounds__(256) void k_binB(const u32* __restrict__ binned,
                                              const int* __restrict__ gcur,
                                              int* __restrict__ rpS,
                                              int* __restrict__ rpE,
                                              float* __restrict__ dis,
                                              u16* __restrict__ cols) {
  __shared__ int cnt[128];
  __shared__ int sc[128];
  __shared__ int lcur[128];
  int b = blockIdx.x;
  int t = threadIdx.x;
  int n0 = b << 7;
  int s = b * BSTRIDE;
  int e = gcur[b];
  if (e > s + BSTRIDE) e = s + BSTRIDE;
  if (t < 128) cnt[t] = 0;
  __syncthreads();
  for (int j = s + t; j < e; j += 256) {
    u32 v = binned[j];
    atomicAdd(&cnt[(int)(v >> 16) - n0], 1);
  }
  __syncthreads();
  if (t < 128) sc[t] = cnt[t];
  __syncthreads();
  for (int off = 1; off < 128; off <<= 1) {
    int tmp = (t >= off && t < 128) ? sc[t - off] : 0;
    __syncthreads();
    if (t < 128) sc[t] += tmp;
    __syncthreads();
  }
  if (t < 128) {
    int n = n0 + t;
    if (n < NODES) {
      int excl = s + sc[t] - cnt[t];
      rpS[n] = excl;
      rpE[n] = excl + cnt[t];
      lcur[t] = excl;
      dis[n] = rsqrtf((float)cnt[t]);
    }
  }
  __syncthreads();
  for (int j = s + t; j < e; j += 256) {
    u32 v = binned[j];
    int local = (int)(v >> 16) - n0;
    int pos = atomicAdd(&lcur[local], 1);
    cols[pos] = (u16)(v & 0xffffu);
  }
}

// ---------------- y2 = diag(dis) * (x @ W) via MFMA, stored bf16 (R4 verbatim) ----------------
__global__ __launch_bounds__(256) void k_gemm(const float* __restrict__ x,
                                              const u16* __restrict__ wts,
                                              const float* __restrict__ dis,
                                              u16* __restrict__ y2) {
  __shared__ u16 xs[64 * 128];
  __shared__ u16 ws[128 * 128];
  const int t = threadIdx.x;
  const int bb = blockIdx.x * 64;

  {
    const uint4* src = (const uint4*)wts;
    uint4* dst = (uint4*)ws;
#pragma unroll
    for (int i = 0; i < 8; ++i) dst[i * 256 + t] = src[i * 256 + t];
  }
  {
#pragma unroll
    for (int i = 0; i < 8; ++i) {
      int goff = i * 4096 + t * 16;
      int row = goff >> 9;
      int gr = bb + row;
      float4 v = make_float4(0.f, 0.f, 0.f, 0.f);
      if (gr < NODES) v = *(const float4*)((const char*)x + (size_t)gr * 512 + (goff & 511));
      u32 lo = (u32)f2bf(v.x) | ((u32)f2bf(v.y) << 16);
      u32 hi = (u32)f2bf(v.z) | ((u32)f2bf(v.w) << 16);
      int colb = (goff & 511) >> 1;
      int off = row * 256 + (colb ^ ((row & 15) << 4));
      *(uint2*)((char*)xs + off) = make_uint2(lo, hi);
    }
  }
  __syncthreads();

  const int w = t >> 6, l = t & 63, m = l & 15, g = l >> 4;
  f32x4 acc[8];
#pragma unroll
  for (int j = 0; j < 8; ++j) acc[j] = (f32x4)0.0f;

  const char* xb = (const char*)xs;
  const char* wb = (const char*)ws;
  const int arow = w * 16 + m;
#pragma unroll
  for (int s = 0; s < 4; ++s) {
    int kx = (g * 16 + s * 64) ^ (m << 4);
    s16x8 a = *(const s16x8*)(xb + arow * 256 + kx);
#pragma unroll
    for (int j = 0; j < 8; ++j) {
      s16x8 b = *(const s16x8*)(wb + (j * 16 + m) * 256 + kx);
      acc[j] = __builtin_amdgcn_mfma_f32_16x16x32_bf16(a, b, acc[j], 0, 0, 0);
    }
  }

  int rbase = bb + w * 16 + g * 4;
  float4 d4 = *(const float4*)&dis[rbase];   // dis region padded past 50000
#pragma unroll
  for (int j = 0; j < 8; ++j) {
#pragma unroll
    for (int r = 0; r < 4; ++r) {
      int gr = rbase + r;
      if (gr < NODES) {
        float dv = (r == 0) ? d4.x : (r == 1) ? d4.y : (r == 2) ? d4.z : d4.w;
        y2[(size_t)gr * 128 + j * 16 + m] = f2bf(acc[j][r] * dv);
      }
    }
  }
}

// ---------------- aggregation (R4 verbatim): 4 edges per wave iter, 16 lanes x 16B per row ----------------
__global__ __launch_bounds__(256) void k_agg(const u16* __restrict__ y2,
                                             const int* __restrict__ rpS,
                                             const int* __restrict__ rpE,
                                             const u16* __restrict__ cols,
                                             const float* __restrict__ dis,
                                             const float* __restrict__ bias,
                                             float* __restrict__ out) {
  int node = (blockIdx.x * 256 + threadIdx.x) >> 6;
  int l = threadIdx.x & 63;
  if (node >= NODES) return;
  int q = l >> 4;
  int m = l & 15;
  int s = rpS[node];
  int e = rpE[node];

  float acc0 = 0.f, acc1 = 0.f, acc2 = 0.f, acc3 = 0.f;
  float acc4 = 0.f, acc5 = 0.f, acc6 = 0.f, acc7 = 0.f;
  const uint4* yb = (const uint4*)y2;

  int c = ((s + q) < e) ? (int)cols[s + q] : 0;
  for (int j = s; j < e; j += 4) {
    bool valid = (j + q) < e;
    int cc = c;
    int jn = j + 4 + q;
    c = (jn < e) ? (int)cols[jn] : 0;
    uint4 v = yb[cc * 16 + m];
    if (valid) {
      acc0 += __uint_as_float(v.x << 16);
      acc1 += __uint_as_float(v.x & 0xffff0000u);
      acc2 += __uint_as_float(v.y << 16);
      acc3 += __uint_as_float(v.y & 0xffff0000u);
      acc4 += __uint_as_float(v.z << 16);
      acc5 += __uint_as_float(v.z & 0xffff0000u);
      acc6 += __uint_as_float(v.w << 16);
      acc7 += __uint_as_float(v.w & 0xffff0000u);
    }
  }
  acc0 += __shfl_xor(acc0, 16); acc0 += __shfl_xor(acc0, 32);
  acc1 += __shfl_xor(acc1, 16); acc1 += __shfl_xor(acc1, 32);
  acc2 += __shfl_xor(acc2, 16); acc2 += __shfl_xor(acc2, 32);
  acc3 += __shfl_xor(acc3, 16); acc3 += __shfl_xor(acc3, 32);
  acc4 += __shfl_xor(acc4, 16); acc4 += __shfl_xor(acc4, 32);
  acc5 += __shfl_xor(acc5, 16); acc5 += __shfl_xor(acc5, 32);
  acc6 += __shfl_xor(acc6, 16); acc6 += __shfl_xor(acc6, 32);
  acc7 += __shfl_xor(acc7, 16); acc7 += __shfl_xor(acc7, 32);

  float di = (e > s) ? dis[node] : 0.0f;
  if (q < 2) {
    float r0 = q ? acc4 : acc0;
    float r1 = q ? acc5 : acc1;
    float r2 = q ? acc6 : acc2;
    float r3 = q ? acc7 : acc3;
    float4 bb = *(const float4*)&bias[m * 8 + q * 4];
    float4 o;
    o.x = bb.x + di * r0;
    o.y = bb.y + di * r1;
    o.z = bb.z + di * r2;
    o.w = bb.w + di * r3;
    *(float4*)&out[(size_t)node * 128 + m * 8 + q * 4] = o;
  }
}

extern "C" void kernel_launch(void* const* d_in, const int* in_sizes, int n_in,
                              void* d_out, int out_size, void* d_ws, size_t ws_size,
                              hipStream_t stream) {
  const float* x    = (const float*)d_in[0];
  const float* W    = (const float*)d_in[1];
  const float* bias = (const float*)d_in[2];
  const int*   erow = (const int*)d_in[3];
  const int*   ecol = (const int*)d_in[4];
  float* out = (float*)d_out;

  char* ws = (char*)d_ws;
  int*   gcursor = (int*)(ws + 0);          // 1.6 KB
  int*   rpS     = (int*)(ws + 4096);       // 200 KB
  int*   rpE     = (int*)(ws + 208896);     // 200 KB
  float* dis     = (float*)(ws + 409600);   // 200 KB (+pad, gemm reads to 50048)
  u16*   wts     = (u16*)(ws + 614400);     // 32 KB
  u32*   binned  = (u32*)(ws + 655360);     // 391*4608*4 = 7,206,912 B
  u16*   cols    = (u16*)(ws + 7864320);    // 391*4608*2 = 3,603,456 B
  u16*   y2      = (u16*)(ws + 11468800);   // 12.8 MB -> ends ~24.3 MB

  k_prep<<<4, 256, 0, stream>>>(W, wts, gcursor);
  k_binA<<<NTILES, 256, 0, stream>>>(erow, ecol, gcursor, binned);
  k_binB<<<NB, 256, 0, stream>>>(binned, gcursor, rpS, rpE, dis, cols);
  k_gemm<<<(NODES + 63) / 64, 256, 0, stream>>>(x, wts, dis, y2);
  k_agg<<<(NODES * 64 + 255) / 256, 256, 0, stream>>>(y2, rpS, rpE, cols, dis, bias, out);
}